// Round 2
// baseline (106.826 us; speedup 1.0000x reference)
//
#include <hip/hip_runtime.h>
#include <hip/hip_bf16.h>

#define LL 128
#define HH 768
#define OFF_REL  0
#define OFF_MASK 131072
#define OFF_HSRC 131840
#define OFF_HTGT 918272
#define SCALEC 2.8853900817779268f   // 2*log2(e):  tanh(x) = 1 - 2/(1+2^(SCALEC*x))

typedef __attribute__((ext_vector_type(8))) short short8;
typedef __attribute__((ext_vector_type(4))) float floatx4;

__device__ inline short8 pack8(float4 lo, float4 hi) {
  union { __hip_bfloat162 h2[4]; short8 s8; } u;
  u.h2[0] = __float22bfloat162_rn(float2{lo.x, lo.y});
  u.h2[1] = __float22bfloat162_rn(float2{lo.z, lo.w});
  u.h2[2] = __float22bfloat162_rn(float2{hi.x, hi.y});
  u.h2[3] = __float22bfloat162_rn(float2{hi.z, hi.w});
  return u.s8;
}

// ---------------- hidden fp32 -> bf16 (tiny: 0.77 MB) ----------------
__global__ __launch_bounds__(256) void cvta_kernel(const float4* __restrict__ hs,
                                                   uint2* __restrict__ ab)
{
  int i = blockIdx.x * 256 + threadIdx.x;   // 49152 float4s
  if (i >= 49152) return;
  float4 v = hs[i];
  union { __hip_bfloat162 h2[2]; uint2 u2; } u;
  u.h2[0] = __float22bfloat162_rn(float2{v.x, v.y});
  u.h2[1] = __float22bfloat162_rn(float2{v.z, v.w});
  ab[i] = u.u2;
}

// ---------------- fused cvt+GEMM: [256x768] x [8448x768]^T, W read fp32 ONCE ----------------
// grid 264 blocks x 32 cols; each block covers all 256 rows. 8 waves: wave = 32 rows x 32 cols.
__global__ __launch_bounds__(512) void gemm_kernel(
    const unsigned short* __restrict__ Ab,
    const float* __restrict__ Wsrc, const float* __restrict__ Wtgt,
    const float* __restrict__ Wd,
    const float* __restrict__ b_src, const float* __restrict__ b_tgt,
    const float* __restrict__ dense_b,
    float* __restrict__ out, float* __restrict__ z)
{
  int nb = blockIdx.x;
  int wave = threadIdx.x >> 6, lane = threadIdx.x & 63;
  int lr = lane & 15, lk8 = (lane >> 4) * 8;

  const float* W; const float* bias; float* dst; int stride; int wrow0;
  if (nb < 96)       { W = Wsrc; bias = b_src;   dst = out + OFF_HSRC; stride = 3072; wrow0 = nb * 32; }
  else if (nb < 192) { W = Wtgt; bias = b_tgt;   dst = out + OFF_HTGT; stride = 3072; wrow0 = nb * 32 - 3072; }
  else               { W = Wd;   bias = dense_b; dst = z;              stride = 2304; wrow0 = nb * 32 - 6144; }

  const unsigned short* ap = Ab + (wave * 32 + lr) * HH + lk8;
  const float* bp = W + (long)(wrow0 + lr) * HH + lk8;

  floatx4 acc[2][2];
  #pragma unroll
  for (int mi = 0; mi < 2; ++mi)
    #pragma unroll
    for (int ni = 0; ni < 2; ++ni)
      acc[mi][ni] = (floatx4){0.f, 0.f, 0.f, 0.f};

  #pragma unroll 4
  for (int k0 = 0; k0 < HH; k0 += 32) {
    short8 a0 = *(const short8*)(ap + k0);
    short8 a1 = *(const short8*)(ap + 16 * HH + k0);
    float4 b0lo = *(const float4*)(bp + k0);
    float4 b0hi = *(const float4*)(bp + k0 + 4);
    float4 b1lo = *(const float4*)(bp + 16 * HH + k0);
    float4 b1hi = *(const float4*)(bp + 16 * HH + k0 + 4);
    short8 b0 = pack8(b0lo, b0hi);
    short8 b1 = pack8(b1lo, b1hi);
    acc[0][0] = __builtin_amdgcn_mfma_f32_16x16x32_bf16(a0, b0, acc[0][0], 0, 0, 0);
    acc[0][1] = __builtin_amdgcn_mfma_f32_16x16x32_bf16(a0, b1, acc[0][1], 0, 0, 0);
    acc[1][0] = __builtin_amdgcn_mfma_f32_16x16x32_bf16(a1, b0, acc[1][0], 0, 0, 0);
    acc[1][1] = __builtin_amdgcn_mfma_f32_16x16x32_bf16(a1, b1, acc[1][1], 0, 0, 0);
  }

  int lrow = (lane >> 4) * 4;
  #pragma unroll
  for (int mi = 0; mi < 2; ++mi)
  #pragma unroll
  for (int ni = 0; ni < 2; ++ni) {
    int col = wrow0 + ni * 16 + lr;          // col within destination matrix
    float bv = bias[col];
    int row0 = wave * 32 + mi * 16 + lrow;
    #pragma unroll
    for (int r2 = 0; r2 < 4; ++r2) {
      dst[(row0 + r2) * stride + col] = acc[mi][ni][r2] + bv;
    }
  }
}

// ---------------- pairwise relation + token-mask head ----------------
// blocks z<8: rel[b,r,s,t] = Wsum - 2*sum_h w[h]/(1+exp2(SCALEC*(hs+ht)))
//   512 threads: half g in {0,1} covers h in [g*384,(g+1)*384), 16x16 (s,t) pairs.
// blocks z==8: mask head.
#define PHC 128
__global__ __launch_bounds__(512) void pair_kernel(
    const float* __restrict__ dout, const float* __restrict__ w_out,
    const float* __restrict__ z, const float* __restrict__ clf_W,
    const float* __restrict__ clf_b, float* __restrict__ out)
{
  int tid = threadIdx.x;

  if (blockIdx.z == 8) {
    // ---- token mask: out[OFF_MASK + o], o in [0,768), o = b*384 + t*128 + lt ----
    int blk = blockIdx.y * 8 + blockIdx.x;     // 0..63
    int wave = tid >> 6, lane = tid & 63;
    int slot = blk * 8 + wave;                 // 0..511
    for (int o = slot; o < 768; o += 512) {
      int b = o / 384, rem = o - b * 384;
      int t = rem >> 7, lt = rem & 127;
      const float* zr = z + (long)(b * LL + lt) * 2304 + t * HH;
      float acc = 0.f;
      for (int h = lane; h < HH; h += 64) {
        float x = zr[h];
        float th = 1.f - 2.f * __builtin_amdgcn_rcpf(1.f + __builtin_amdgcn_exp2f(SCALEC * x));
        acc = fmaf(clf_W[h], th, acc);
      }
      #pragma unroll
      for (int d = 32; d; d >>= 1) acc += __shfl_down(acc, d);
      if (lane == 0) out[OFF_MASK + o] = acc + clf_b[0];
    }
    return;
  }

  __shared__ float sA[2][16][PHC + 4];
  __shared__ float sB[2][16][PHC + 4];
  __shared__ __align__(16) float sW[2][PHC];
  __shared__ float sRed[256];
  __shared__ float sWsum;

  int g = tid >> 8, u = tid & 255;
  int s_ = u >> 4, t_ = u & 15;
  int t0 = blockIdx.x * 16, s0 = blockIdx.y * 16;
  int br = blockIdx.z, b = br >> 2, r = br & 3;
  const float* hsrc = dout + OFF_HSRC;
  const float* htgt = dout + OFF_HTGT;

  if (tid < 64) {
    float wsm = 0.f;
    for (int h = tid; h < HH; h += 64) wsm += w_out[h];
    #pragma unroll
    for (int d = 32; d; d >>= 1) wsm += __shfl_down(wsm, d);
    if (tid == 0) sWsum = wsm;
  }

  // staging pointers: this thread stages row (u>>4) of its half's A and B tiles
  const float* pa = hsrc + (long)((b * LL + s0 + s_) * 4 + r) * HH + g * 384;
  const float* pb = htgt + (long)((b * LL + t0 + s_) * 4 + r) * HH + g * 384;
  float acc0 = 0.f, acc1 = 0.f;

  for (int c = 0; c < 384; c += PHC) {
    __syncthreads();
    {
      int cc = t_ * 8;
      float4 va0 = *(const float4*)(pa + c + cc);
      float4 va1 = *(const float4*)(pa + c + cc + 4);
      float4 vb0 = *(const float4*)(pb + c + cc);
      float4 vb1 = *(const float4*)(pb + c + cc + 4);
      va0.x *= SCALEC; va0.y *= SCALEC; va0.z *= SCALEC; va0.w *= SCALEC;
      va1.x *= SCALEC; va1.y *= SCALEC; va1.z *= SCALEC; va1.w *= SCALEC;
      vb0.x *= SCALEC; vb0.y *= SCALEC; vb0.z *= SCALEC; vb0.w *= SCALEC;
      vb1.x *= SCALEC; vb1.y *= SCALEC; vb1.z *= SCALEC; vb1.w *= SCALEC;
      *(float4*)&sA[g][s_][cc]     = va0;
      *(float4*)&sA[g][s_][cc + 4] = va1;
      *(float4*)&sB[g][s_][cc]     = vb0;
      *(float4*)&sB[g][s_][cc + 4] = vb1;
      if (u < 32) *(float4*)&sW[g][u * 4] = *(const float4*)(w_out + g * 384 + c + u * 4);
    }
    __syncthreads();
    #pragma unroll 8
    for (int h = 0; h < PHC; h += 4) {
      float4 va = *(const float4*)&sA[g][s_][h];
      float4 vb = *(const float4*)&sB[g][t_][h];
      float4 vw = *(const float4*)&sW[g][h];
      acc0 = fmaf(vw.x, __builtin_amdgcn_rcpf(1.f + __builtin_amdgcn_exp2f(va.x + vb.x)), acc0);
      acc1 = fmaf(vw.y, __builtin_amdgcn_rcpf(1.f + __builtin_amdgcn_exp2f(va.y + vb.y)), acc1);
      acc0 = fmaf(vw.z, __builtin_amdgcn_rcpf(1.f + __builtin_amdgcn_exp2f(va.z + vb.z)), acc0);
      acc1 = fmaf(vw.w, __builtin_amdgcn_rcpf(1.f + __builtin_amdgcn_exp2f(va.w + vb.w)), acc1);
    }
  }

  float acc = acc0 + acc1;
  if (g == 1) sRed[u] = acc;
  __syncthreads();
  if (g == 0) {
    float res = sWsum - 2.f * (acc + sRed[u]);
    out[((long)br * LL + (s0 + s_)) * LL + (t0 + t_)] = res;
  }
}

extern "C" void kernel_launch(void* const* d_in, const int* in_sizes, int n_in,
                              void* d_out, int out_size, void* d_ws, size_t ws_size,
                              hipStream_t stream)
{
  const float* hidden  = (const float*)d_in[0];
  const float* W_src   = (const float*)d_in[1];
  const float* b_src   = (const float*)d_in[2];
  const float* W_tgt   = (const float*)d_in[3];
  const float* b_tgt   = (const float*)d_in[4];
  const float* w_out   = (const float*)d_in[5];
  const float* dense_W = (const float*)d_in[6];
  const float* dense_b = (const float*)d_in[7];
  const float* clf_W   = (const float*)d_in[8];
  const float* clf_b   = (const float*)d_in[9];
  float* out = (float*)d_out;
  char* ws = (char*)d_ws;

  unsigned short* Ab = (unsigned short*)ws;            // 256x768 bf16 = 384 KB
  float* z = (float*)(ws + 393216);                    // 256x2304 f32 = 2.36 MB

  hipLaunchKernelGGL(cvta_kernel, dim3(192), dim3(256), 0, stream,
      (const float4*)hidden, (uint2*)Ab);
  hipLaunchKernelGGL(gemm_kernel, dim3(264), dim3(512), 0, stream,
      Ab, W_src, W_tgt, dense_W, b_src, b_tgt, dense_b, out, z);
  hipLaunchKernelGGL(pair_kernel, dim3(8, 8, 9), dim3(512), 0, stream,
      out, w_out, z, clf_W, clf_b, out + OFF_REL);
}

// Round 3
// 72.849 us; speedup vs baseline: 1.4664x; 1.4664x over previous
//
#include <hip/hip_runtime.h>
#include <hip/hip_bf16.h>

#define LL 128
#define HH 768
#define OFF_REL  0
#define OFF_MASK 131072
#define OFF_HSRC 131840
#define OFF_HTGT 918272
#define SCALEC 2.8853900817779268f   // 2*log2(e):  e^{2x} = exp2(SCALEC*x)

typedef __attribute__((ext_vector_type(8))) short short8;
typedef __attribute__((ext_vector_type(4))) float floatx4;

__device__ inline unsigned short f2bf(float f) {
  unsigned u = __float_as_uint(f);
  u += 0x7FFFu + ((u >> 16) & 1u);
  return (unsigned short)(u >> 16);
}
struct us4 { unsigned short x, y, z, w; };

// ---------------- fp32 -> bf16: hidden + all three weights (40 MB traffic) ----------------
__global__ __launch_bounds__(256) void cvt_kernel(
    const float4* __restrict__ hs, const float4* __restrict__ wsrc,
    const float4* __restrict__ wtgt, const float4* __restrict__ wd,
    us4* __restrict__ ab, us4* __restrict__ wb)
{
  const int n0 = 49152;               // hidden: 196608/4
  const int n1 = n0 + 589824;         // W_src
  const int n2 = n1 + 589824;         // W_tgt
  const int n3 = n2 + 442368;         // dense_W
  int stride = gridDim.x * blockDim.x;
  for (int i = blockIdx.x * blockDim.x + threadIdx.x; i < n3; i += stride) {
    const float4* src; us4* dst;
    if (i < n0)      { src = hs   + i;        dst = ab + i; }
    else if (i < n1) { src = wsrc + (i - n0); dst = wb + (i - n0); }
    else if (i < n2) { src = wtgt + (i - n1); dst = wb + 589824 + (i - n1); }
    else             { src = wd   + (i - n2); dst = wb + 1179648 + (i - n2); }
    float4 v = *src;
    us4 o; o.x = f2bf(v.x); o.y = f2bf(v.y); o.z = f2bf(v.z); o.w = f2bf(v.w);
    *dst = o;
  }
}

// ---------------- bf16 GEMM [256x768] x [8448x768]^T + bias + E=exp2 epilogue ----------------
// grid (132, 4): block = 64 rows x 64 cols, 4 waves of 32x32. Explicit 2-stage reg pipeline.
__global__ __launch_bounds__(256) void gemm_kernel(
    const unsigned short* __restrict__ Ab, const unsigned short* __restrict__ Wb,
    const float* __restrict__ b_src, const float* __restrict__ b_tgt,
    const float* __restrict__ dense_b,
    float* __restrict__ out, float* __restrict__ z,
    float* __restrict__ Es, float* __restrict__ Et)
{
  int nb = blockIdx.x;                 // 0..131  (col block of 64)
  int mb = blockIdx.y * 64;
  int wave = threadIdx.x >> 6, lane = threadIdx.x & 63;
  int wm = (wave >> 1) * 32, wn = (wave & 1) * 32;
  int lr = lane & 15, lk8 = (lane >> 4) * 8;

  const unsigned short* ap = Ab + (mb + wm + lr) * HH + lk8;
  const unsigned short* bp = Wb + (long)(nb * 64 + wn + lr) * HH + lk8;

  floatx4 acc[2][2];
  #pragma unroll
  for (int mi = 0; mi < 2; ++mi)
    #pragma unroll
    for (int ni = 0; ni < 2; ++ni)
      acc[mi][ni] = (floatx4){0.f, 0.f, 0.f, 0.f};

  short8 a0 = *(const short8*)(ap);
  short8 a1 = *(const short8*)(ap + 16 * HH);
  short8 b0 = *(const short8*)(bp);
  short8 b1 = *(const short8*)(bp + 16 * HH);
  #pragma unroll
  for (int k0 = 32; k0 <= HH; k0 += 32) {
    short8 na0, na1, nb0, nb1;
    if (k0 < HH) {
      na0 = *(const short8*)(ap + k0);
      na1 = *(const short8*)(ap + k0 + 16 * HH);
      nb0 = *(const short8*)(bp + k0);
      nb1 = *(const short8*)(bp + k0 + 16 * HH);
    }
    acc[0][0] = __builtin_amdgcn_mfma_f32_16x16x32_bf16(a0, b0, acc[0][0], 0, 0, 0);
    acc[0][1] = __builtin_amdgcn_mfma_f32_16x16x32_bf16(a0, b1, acc[0][1], 0, 0, 0);
    acc[1][0] = __builtin_amdgcn_mfma_f32_16x16x32_bf16(a1, b0, acc[1][0], 0, 0, 0);
    acc[1][1] = __builtin_amdgcn_mfma_f32_16x16x32_bf16(a1, b1, acc[1][1], 0, 0, 0);
    a0 = na0; a1 = na1; b0 = nb0; b1 = nb1;
  }

  // epilogue: block-uniform destination (64-col blocks align to 3072 boundaries)
  int lrow = (lane >> 4) * 4;
  #pragma unroll
  for (int mi = 0; mi < 2; ++mi)
  #pragma unroll
  for (int ni = 0; ni < 2; ++ni) {
    int colg = nb * 64 + wn + ni * 16 + lr;
    int row0 = mb + wm + mi * 16 + lrow;
    if (nb < 48) {
      float bv = b_src[colg];
      #pragma unroll
      for (int r2 = 0; r2 < 4; ++r2) {
        int row = row0 + r2;
        float v = acc[mi][ni][r2] + bv;
        out[OFF_HSRC + row * 3072 + colg] = v;
        Es[row * 3072 + colg] = __builtin_amdgcn_exp2f(SCALEC * v);
      }
    } else if (nb < 96) {
      int c = colg - 3072;
      float bv = b_tgt[c];
      #pragma unroll
      for (int r2 = 0; r2 < 4; ++r2) {
        int row = row0 + r2;
        float v = acc[mi][ni][r2] + bv;
        out[OFF_HTGT + row * 3072 + c] = v;
        Et[row * 3072 + c] = __builtin_amdgcn_exp2f(SCALEC * v);
      }
    } else {
      int c = colg - 6144;
      float bv = dense_b[c];
      #pragma unroll
      for (int r2 = 0; r2 < 4; ++r2)
        z[(row0 + r2) * 2304 + c] = acc[mi][ni][r2] + bv;
    }
  }
}

// ---------------- pairwise relation + token-mask head ----------------
// rel[b,r,s,t] = Wsum - 2*sum_h w[h] / (1 + Es[s,h]*Et[t,h])
// 512 threads: g in {0,1} covers h in [g*384,(g+1)*384); 16x16 (s,t) pairs each.
#define PHC 128
__global__ __launch_bounds__(512) void pair_kernel(
    const float* __restrict__ Es, const float* __restrict__ Et,
    const float* __restrict__ w_out,
    const float* __restrict__ z, const float* __restrict__ clf_W,
    const float* __restrict__ clf_b, float* __restrict__ out)
{
  int tid = threadIdx.x;

  if (blockIdx.z == 8) {
    // token mask head: 768 rows, 8 waves per block x 64 blocks
    int blk = blockIdx.y * 8 + blockIdx.x;
    int wave = tid >> 6, lane = tid & 63;
    int slot = blk * 8 + wave;
    for (int o = slot; o < 768; o += 512) {
      int b = o / 384, rem = o - b * 384;
      int t = rem >> 7, lt = rem & 127;
      const float* zr = z + (long)(b * LL + lt) * 2304 + t * HH;
      float acc = 0.f;
      for (int h = lane; h < HH; h += 64) {
        float x = zr[h];
        float th = 1.f - 2.f * __builtin_amdgcn_rcpf(1.f + __builtin_amdgcn_exp2f(SCALEC * x));
        acc = fmaf(clf_W[h], th, acc);
      }
      #pragma unroll
      for (int d = 32; d; d >>= 1) acc += __shfl_down(acc, d);
      if (lane == 0) out[OFF_MASK + o] = acc + clf_b[0];
    }
    return;
  }

  __shared__ float sA[2][16][PHC + 4];
  __shared__ float sB[2][16][PHC + 4];
  __shared__ __align__(16) float sW[2][PHC];
  __shared__ float sRed[256];
  __shared__ float sWsum;

  int g = tid >> 8, u = tid & 255;
  int s_ = u >> 4, t_ = u & 15;
  int t0 = blockIdx.x * 16, s0 = blockIdx.y * 16;
  int br = blockIdx.z, b = br >> 2, r = br & 3;

  if (tid < 64) {
    float wsm = 0.f;
    for (int h = tid; h < HH; h += 64) wsm += w_out[h];
    #pragma unroll
    for (int d = 32; d; d >>= 1) wsm += __shfl_down(wsm, d);
    if (tid == 0) sWsum = wsm;
  }

  const float* pa = Es + (long)(b * LL + s0 + s_) * 3072 + r * HH + g * 384;
  const float* pb = Et + (long)(b * LL + t0 + s_) * 3072 + r * HH + g * 384;
  float acc0 = 0.f, acc1 = 0.f;

  for (int c = 0; c < 384; c += PHC) {
    __syncthreads();
    {
      int cc = t_ * 8;
      *(float4*)&sA[g][s_][cc]     = *(const float4*)(pa + c + cc);
      *(float4*)&sA[g][s_][cc + 4] = *(const float4*)(pa + c + cc + 4);
      *(float4*)&sB[g][s_][cc]     = *(const float4*)(pb + c + cc);
      *(float4*)&sB[g][s_][cc + 4] = *(const float4*)(pb + c + cc + 4);
      if (u < 32) *(float4*)&sW[g][u * 4] = *(const float4*)(w_out + g * 384 + c + u * 4);
    }
    __syncthreads();
    #pragma unroll 8
    for (int h = 0; h < PHC; h += 4) {
      float4 es = *(const float4*)&sA[g][s_][h];
      float4 et = *(const float4*)&sB[g][t_][h];
      float4 vw = *(const float4*)&sW[g][h];
      acc0 = fmaf(vw.x, __builtin_amdgcn_rcpf(fmaf(es.x, et.x, 1.f)), acc0);
      acc1 = fmaf(vw.y, __builtin_amdgcn_rcpf(fmaf(es.y, et.y, 1.f)), acc1);
      acc0 = fmaf(vw.z, __builtin_amdgcn_rcpf(fmaf(es.z, et.z, 1.f)), acc0);
      acc1 = fmaf(vw.w, __builtin_amdgcn_rcpf(fmaf(es.w, et.w, 1.f)), acc1);
    }
  }

  float acc = acc0 + acc1;
  if (g == 1) sRed[u] = acc;
  __syncthreads();
  if (g == 0) {
    float res = sWsum - 2.f * (acc + sRed[u]);
    out[((long)br * LL + (s0 + s_)) * LL + (t0 + t_)] = res;
  }
}

extern "C" void kernel_launch(void* const* d_in, const int* in_sizes, int n_in,
                              void* d_out, int out_size, void* d_ws, size_t ws_size,
                              hipStream_t stream)
{
  const float* hidden  = (const float*)d_in[0];
  const float* W_src   = (const float*)d_in[1];
  const float* b_src   = (const float*)d_in[2];
  const float* W_tgt   = (const float*)d_in[3];
  const float* b_tgt   = (const float*)d_in[4];
  const float* w_out   = (const float*)d_in[5];
  const float* dense_W = (const float*)d_in[6];
  const float* dense_b = (const float*)d_in[7];
  const float* clf_W   = (const float*)d_in[8];
  const float* clf_b   = (const float*)d_in[9];
  float* out = (float*)d_out;
  char* ws = (char*)d_ws;

  unsigned short* Ab = (unsigned short*)ws;            // 256x768 bf16   [0, 384K)
  unsigned short* Wb = (unsigned short*)(ws + 393216); // 8448x768 bf16  [384K, ~13M)
  float* z  = (float*)(ws + 13369344);                 // 256x2304 f32
  float* Es = (float*)(ws + 15728640);                 // 256x3072 f32
  float* Et = (float*)(ws + 18874368);                 // 256x3072 f32

  hipLaunchKernelGGL(cvt_kernel, dim3(2048), dim3(256), 0, stream,
      (const float4*)hidden, (const float4*)W_src, (const float4*)W_tgt,
      (const float4*)dense_W, (us4*)Ab, (us4*)Wb);
  hipLaunchKernelGGL(gemm_kernel, dim3(132, 4), dim3(256), 0, stream,
      Ab, Wb, b_src, b_tgt, dense_b, out, z, Es, Et);
  hipLaunchKernelGGL(pair_kernel, dim3(8, 8, 9), dim3(512), 0, stream,
      Es, Et, w_out, z, clf_W, clf_b, out + OFF_REL);
}

// Round 4
// 63.162 us; speedup vs baseline: 1.6913x; 1.1534x over previous
//
#include <hip/hip_runtime.h>
#include <hip/hip_bf16.h>

#define LL 128
#define HH 768
#define OFF_REL  0
#define OFF_MASK 131072
#define OFF_HSRC 131840
#define OFF_HTGT 918272
#define SCALEC 2.8853900817779268f   // 2*log2(e):  e^{2x} = exp2(SCALEC*x)

typedef __attribute__((ext_vector_type(8))) short short8;
typedef __attribute__((ext_vector_type(4))) float floatx4;

// ---------------- hidden fp32 -> bf16 (1.2 MB traffic) ----------------
__global__ __launch_bounds__(256) void cvta_kernel(const float4* __restrict__ hs,
                                                   uint2* __restrict__ ab)
{
  int i = blockIdx.x * 256 + threadIdx.x;   // 49152 float4s
  if (i >= 49152) return;
  float4 v = hs[i];
  union { __hip_bfloat162 h2[2]; uint2 u2; } u;
  u.h2[0] = __float22bfloat162_rn(float2{v.x, v.y});
  u.h2[1] = __float22bfloat162_rn(float2{v.z, v.w});
  ab[i] = u.u2;
}

// ---------------- GEMM: A[256x768]bf16 x W[8448x768]^T fp32-read-once ----------------
// 264 blocks x 32 cols, 512 thr (8 waves x 32 rows). W staged fp32->bf16 via LDS dbuf.
#define KPAD 72
__global__ __launch_bounds__(512) void gemm_kernel(
    const unsigned short* __restrict__ Ab,
    const float* __restrict__ Wsrc, const float* __restrict__ Wtgt,
    const float* __restrict__ Wd,
    const float* __restrict__ b_src, const float* __restrict__ b_tgt,
    const float* __restrict__ dense_b,
    float* __restrict__ out, float* __restrict__ z,
    float* __restrict__ Es, float* __restrict__ Et)
{
  __shared__ unsigned short sB[2][32][KPAD];
  int nb = blockIdx.x;
  int tid = threadIdx.x;
  int wave = tid >> 6, lane = tid & 63;

  const float* W; int wrow0;
  if (nb < 96)       { W = Wsrc; wrow0 = nb * 32; }
  else if (nb < 192) { W = Wtgt; wrow0 = (nb - 96) * 32; }
  else               { W = Wd;   wrow0 = (nb - 192) * 32; }

  // staging: thread -> (col sc, k-quad sq)
  int sc = tid >> 4, sq = (tid & 15) * 4;
  const float* wp = W + (long)(wrow0 + sc) * HH + sq;

  // fragments
  int lr = lane & 15, lk8 = (lane >> 4) * 8;
  const unsigned short* ap = Ab + (wave * 32 + lr) * HH + lk8;

  floatx4 acc[2][2];
  #pragma unroll
  for (int mi = 0; mi < 2; ++mi)
    #pragma unroll
    for (int ni = 0; ni < 2; ++ni)
      acc[mi][ni] = (floatx4){0.f, 0.f, 0.f, 0.f};

  // stage chunk 0
  {
    float4 v = *(const float4*)(wp);
    union { __hip_bfloat162 h2[2]; uint2 u2; } u;
    u.h2[0] = __float22bfloat162_rn(float2{v.x, v.y});
    u.h2[1] = __float22bfloat162_rn(float2{v.z, v.w});
    *(uint2*)&sB[0][sc][sq] = u.u2;
  }
  __syncthreads();

  for (int ch = 0; ch < 12; ++ch) {
    int cur = ch & 1;
    float4 nv;
    if (ch < 11) nv = *(const float4*)(wp + (ch + 1) * 64);   // issue next-chunk load early

    #pragma unroll
    for (int ks = 0; ks < 2; ++ks) {
      int k0 = ch * 64 + ks * 32;
      short8 a0 = *(const short8*)(ap + k0);
      short8 a1 = *(const short8*)(ap + k0 + 16 * HH);
      short8 b0 = *(const short8*)(&sB[cur][lr][ks * 32 + lk8]);
      short8 b1 = *(const short8*)(&sB[cur][16 + lr][ks * 32 + lk8]);
      acc[0][0] = __builtin_amdgcn_mfma_f32_16x16x32_bf16(a0, b0, acc[0][0], 0, 0, 0);
      acc[0][1] = __builtin_amdgcn_mfma_f32_16x16x32_bf16(a0, b1, acc[0][1], 0, 0, 0);
      acc[1][0] = __builtin_amdgcn_mfma_f32_16x16x32_bf16(a1, b0, acc[1][0], 0, 0, 0);
      acc[1][1] = __builtin_amdgcn_mfma_f32_16x16x32_bf16(a1, b1, acc[1][1], 0, 0, 0);
    }
    if (ch < 11) {
      union { __hip_bfloat162 h2[2]; uint2 u2; } u;
      u.h2[0] = __float22bfloat162_rn(float2{nv.x, nv.y});
      u.h2[1] = __float22bfloat162_rn(float2{nv.z, nv.w});
      *(uint2*)&sB[cur ^ 1][sc][sq] = u.u2;
    }
    __syncthreads();
  }

  // epilogue
  int lrow = (lane >> 4) * 4;
  #pragma unroll
  for (int mi = 0; mi < 2; ++mi)
  #pragma unroll
  for (int ni = 0; ni < 2; ++ni) {
    int col  = wrow0 + ni * 16 + lr;
    int row0 = wave * 32 + mi * 16 + lrow;
    if (nb < 96) {
      float bv = b_src[col];
      #pragma unroll
      for (int r2 = 0; r2 < 4; ++r2) {
        int row = row0 + r2;
        float v = acc[mi][ni][r2] + bv;
        out[OFF_HSRC + row * 3072 + col] = v;
        Es[row * 3072 + col] = __builtin_amdgcn_exp2f(SCALEC * v);
      }
    } else if (nb < 192) {
      float bv = b_tgt[col];
      #pragma unroll
      for (int r2 = 0; r2 < 4; ++r2) {
        int row = row0 + r2;
        float v = acc[mi][ni][r2] + bv;
        out[OFF_HTGT + row * 3072 + col] = v;
        Et[row * 3072 + col] = __builtin_amdgcn_exp2f(SCALEC * v);
      }
    } else {
      float bv = dense_b[col];
      #pragma unroll
      for (int r2 = 0; r2 < 4; ++r2)
        z[(row0 + r2) * 2304 + col] = acc[mi][ni][r2] + bv;
    }
  }
}

// ---------------- pairwise relation + token-mask head ----------------
// rel[b,r,s,t] = Wsum - 2*sum_h w[h] / (1 + Es[s,h]*Et[t,h])
// 512 thr: wave g in [0,8) owns h-subrange; lane owns 2s x 2t of a 16x16 tile.
#define PHC 256
__global__ __launch_bounds__(512) void pair_kernel(
    const float* __restrict__ Es, const float* __restrict__ Et,
    const float* __restrict__ w_out,
    const float* __restrict__ z, const float* __restrict__ clf_W,
    const float* __restrict__ clf_b, float* __restrict__ out)
{
  int tid = threadIdx.x;

  if (blockIdx.z == 8) {
    // token mask head
    int blk = blockIdx.y * 8 + blockIdx.x;
    int wave = tid >> 6, lane = tid & 63;
    int slot = blk * 8 + wave;
    for (int o = slot; o < 768; o += 512) {
      int b = o / 384, rem = o - b * 384;
      int t = rem >> 7, lt = rem & 127;
      const float* zr = z + (long)(b * LL + lt) * 2304 + t * HH;
      float acc = 0.f;
      for (int h = lane; h < HH; h += 64) {
        float x = zr[h];
        float th = 1.f - 2.f * __builtin_amdgcn_rcpf(1.f + __builtin_amdgcn_exp2f(SCALEC * x));
        acc = fmaf(clf_W[h], th, acc);
      }
      #pragma unroll
      for (int d = 32; d; d >>= 1) acc += __shfl_down(acc, d);
      if (lane == 0) out[OFF_MASK + o] = acc + clf_b[0];
    }
    return;
  }

  __shared__ float sA[16][PHC + 4];
  __shared__ float sB[16][PHC + 4];
  __shared__ __align__(16) float sW[PHC];
  __shared__ float sRed[2048];
  __shared__ float sWsum;

  int g = tid >> 6, lane = tid & 63;
  int sq = lane >> 3, tq = lane & 7;
  int t0 = blockIdx.x * 16, s0 = blockIdx.y * 16;
  int br = blockIdx.z, bb = br >> 2, r = br & 3;

  if (tid < 64) {
    float wsm = 0.f;
    for (int h = tid; h < HH; h += 64) wsm += w_out[h];
    #pragma unroll
    for (int d = 32; d; d >>= 1) wsm += __shfl_down(wsm, d);
    if (tid == 0) sWsum = wsm;
  }

  float a00 = 0.f, a01 = 0.f, a10 = 0.f, a11 = 0.f;

  for (int c = 0; c < HH; c += PHC) {
    __syncthreads();
    // stage 16 rows x 256 cols of Es and Et (2 float4 each per thread per matrix)
    #pragma unroll
    for (int j = 0; j < 2; ++j) {
      int idx = tid * 2 + j;
      int row = idx >> 6, col4 = (idx & 63) * 4;
      *(float4*)&sA[row][col4] =
          *(const float4*)(Es + (long)(bb * LL + s0 + row) * 3072 + r * HH + c + col4);
      *(float4*)&sB[row][col4] =
          *(const float4*)(Et + (long)(bb * LL + t0 + row) * 3072 + r * HH + c + col4);
    }
    if (tid < 64) *(float4*)&sW[tid * 4] = *(const float4*)(w_out + c + tid * 4);
    __syncthreads();

    const float* pA0 = &sA[2 * sq][g * 32];
    const float* pA1 = &sA[2 * sq + 1][g * 32];
    const float* pB0 = &sB[2 * tq][g * 32];
    const float* pB1 = &sB[2 * tq + 1][g * 32];
    const float* pW  = &sW[g * 32];
    #pragma unroll
    for (int hh = 0; hh < 32; hh += 4) {
      float4 e0 = *(const float4*)(pA0 + hh);
      float4 e1 = *(const float4*)(pA1 + hh);
      float4 f0 = *(const float4*)(pB0 + hh);
      float4 f1 = *(const float4*)(pB1 + hh);
      float4 vw = *(const float4*)(pW + hh);
      a00 = fmaf(vw.x, __builtin_amdgcn_rcpf(fmaf(e0.x, f0.x, 1.f)), a00);
      a01 = fmaf(vw.x, __builtin_amdgcn_rcpf(fmaf(e0.x, f1.x, 1.f)), a01);
      a10 = fmaf(vw.x, __builtin_amdgcn_rcpf(fmaf(e1.x, f0.x, 1.f)), a10);
      a11 = fmaf(vw.x, __builtin_amdgcn_rcpf(fmaf(e1.x, f1.x, 1.f)), a11);
      a00 = fmaf(vw.y, __builtin_amdgcn_rcpf(fmaf(e0.y, f0.y, 1.f)), a00);
      a01 = fmaf(vw.y, __builtin_amdgcn_rcpf(fmaf(e0.y, f1.y, 1.f)), a01);
      a10 = fmaf(vw.y, __builtin_amdgcn_rcpf(fmaf(e1.y, f0.y, 1.f)), a10);
      a11 = fmaf(vw.y, __builtin_amdgcn_rcpf(fmaf(e1.y, f1.y, 1.f)), a11);
      a00 = fmaf(vw.z, __builtin_amdgcn_rcpf(fmaf(e0.z, f0.z, 1.f)), a00);
      a01 = fmaf(vw.z, __builtin_amdgcn_rcpf(fmaf(e0.z, f1.z, 1.f)), a01);
      a10 = fmaf(vw.z, __builtin_amdgcn_rcpf(fmaf(e1.z, f0.z, 1.f)), a10);
      a11 = fmaf(vw.z, __builtin_amdgcn_rcpf(fmaf(e1.z, f1.z, 1.f)), a11);
      a00 = fmaf(vw.w, __builtin_amdgcn_rcpf(fmaf(e0.w, f0.w, 1.f)), a00);
      a01 = fmaf(vw.w, __builtin_amdgcn_rcpf(fmaf(e0.w, f1.w, 1.f)), a01);
      a10 = fmaf(vw.w, __builtin_amdgcn_rcpf(fmaf(e1.w, f0.w, 1.f)), a10);
      a11 = fmaf(vw.w, __builtin_amdgcn_rcpf(fmaf(e1.w, f1.w, 1.f)), a11);
    }
  }

  // reduce over the 8 h-slices
  int p = lane;
  sRed[(p * 4 + 0) * 8 + g] = a00;
  sRed[(p * 4 + 1) * 8 + g] = a01;
  sRed[(p * 4 + 2) * 8 + g] = a10;
  sRed[(p * 4 + 3) * 8 + g] = a11;
  __syncthreads();
  if (tid < 256) {
    int s = tid >> 4, t = tid & 15;
    int pp = (s >> 1) * 8 + (t >> 1);
    int sl = (s & 1) * 2 + (t & 1);
    const float* rp = &sRed[(pp * 4 + sl) * 8];
    float sum = rp[0] + rp[1] + rp[2] + rp[3] + rp[4] + rp[5] + rp[6] + rp[7];
    out[((long)br * LL + (s0 + s)) * LL + (t0 + t)] = sWsum - 2.f * sum;
  }
}

extern "C" void kernel_launch(void* const* d_in, const int* in_sizes, int n_in,
                              void* d_out, int out_size, void* d_ws, size_t ws_size,
                              hipStream_t stream)
{
  const float* hidden  = (const float*)d_in[0];
  const float* W_src   = (const float*)d_in[1];
  const float* b_src   = (const float*)d_in[2];
  const float* W_tgt   = (const float*)d_in[3];
  const float* b_tgt   = (const float*)d_in[4];
  const float* w_out   = (const float*)d_in[5];
  const float* dense_W = (const float*)d_in[6];
  const float* dense_b = (const float*)d_in[7];
  const float* clf_W   = (const float*)d_in[8];
  const float* clf_b   = (const float*)d_in[9];
  float* out = (float*)d_out;
  char* ws = (char*)d_ws;

  unsigned short* Ab = (unsigned short*)ws;        // 256x768 bf16  [0, 384K)
  float* z  = (float*)(ws + 393216);               // 256x2304 f32  (2.36 MB)
  float* Es = (float*)(ws + 2752512);              // 256x3072 f32  (3.15 MB)
  float* Et = (float*)(ws + 5898240);              // 256x3072 f32  (3.15 MB)

  hipLaunchKernelGGL(cvta_kernel, dim3(192), dim3(256), 0, stream,
      (const float4*)hidden, (uint2*)Ab);
  hipLaunchKernelGGL(gemm_kernel, dim3(264), dim3(512), 0, stream,
      Ab, W_src, W_tgt, dense_W, b_src, b_tgt, dense_b, out, z, Es, Et);
  hipLaunchKernelGGL(pair_kernel, dim3(8, 8, 9), dim3(512), 0, stream,
      Es, Et, w_out, z, clf_W, clf_b, out + OFF_REL);
}

// Round 5
// 58.246 us; speedup vs baseline: 1.8340x; 1.0844x over previous
//
#include <hip/hip_runtime.h>
#include <hip/hip_bf16.h>

#define LL 128
#define HH 768
#define OFF_REL  0
#define OFF_MASK 131072
#define OFF_HSRC 131840
#define OFF_HTGT 918272
#define SCALEC 2.8853900817779268f   // 2*log2(e):  e^{2x} = exp2(SCALEC*x)

typedef __attribute__((ext_vector_type(8))) short short8;
typedef __attribute__((ext_vector_type(4))) float floatx4;

// ---------------- hidden fp32 -> bf16 (1.2 MB traffic) ----------------
__global__ __launch_bounds__(256) void cvta_kernel(const float4* __restrict__ hs,
                                                   uint2* __restrict__ ab)
{
  int i = blockIdx.x * 256 + threadIdx.x;   // 49152 float4s
  if (i >= 49152) return;
  float4 v = hs[i];
  union { __hip_bfloat162 h2[2]; uint2 u2; } u;
  u.h2[0] = __float22bfloat162_rn(float2{v.x, v.y});
  u.h2[1] = __float22bfloat162_rn(float2{v.z, v.w});
  ab[i] = u.u2;
}

// ---------------- GEMM: A[256x768]bf16 x W[8448x768]^T, W fp32 read once ----------------
// 264 blocks x 32 cols, 512 thr (8 waves x 32 rows each).
// ALL 12 W-chunks prefetched to registers up front (12 loads in flight), then
// LDS dbuf staged from regs; A fragments double-buffered in regs.
#define KPAD 72
__global__ __launch_bounds__(512, 2) void gemm_kernel(
    const unsigned short* __restrict__ Ab,
    const float* __restrict__ Wsrc, const float* __restrict__ Wtgt,
    const float* __restrict__ Wd,
    const float* __restrict__ b_src, const float* __restrict__ b_tgt,
    const float* __restrict__ dense_b,
    float* __restrict__ out, float* __restrict__ z,
    float* __restrict__ Es, float* __restrict__ Et)
{
  __shared__ unsigned short sB[2][32][KPAD];
  int nb = blockIdx.x;
  int tid = threadIdx.x;
  int wave = tid >> 6, lane = tid & 63;

  const float* W; int wrow0;
  if (nb < 96)       { W = Wsrc; wrow0 = nb * 32; }
  else if (nb < 192) { W = Wtgt; wrow0 = (nb - 96) * 32; }
  else               { W = Wd;   wrow0 = (nb - 192) * 32; }

  // staging role: thread -> (col sc, k-quad sq)
  int sc = tid >> 4, sq = (tid & 15) * 4;
  const float* wp = W + (long)(wrow0 + sc) * HH + sq;

  // prefetch ALL W data for this block into registers (12 x float4 = 48 VGPR)
  float4 wr[12];
  #pragma unroll
  for (int ch = 0; ch < 12; ++ch) wr[ch] = *(const float4*)(wp + ch * 64);

  // MFMA fragment addressing
  int lr = lane & 15, lk8 = (lane >> 4) * 8;
  const unsigned short* ap = Ab + (wave * 32 + lr) * HH + lk8;

  floatx4 acc[2][2];
  #pragma unroll
  for (int mi = 0; mi < 2; ++mi)
    #pragma unroll
    for (int ni = 0; ni < 2; ++ni)
      acc[mi][ni] = (floatx4){0.f, 0.f, 0.f, 0.f};

  // A fragments, double-buffered: [buf][ks][mi]
  short8 a[2][2][2];
  #pragma unroll
  for (int ks = 0; ks < 2; ++ks) {
    a[0][ks][0] = *(const short8*)(ap + ks * 32);
    a[0][ks][1] = *(const short8*)(ap + ks * 32 + 16 * HH);
  }

  // stage chunk 0 from regs
  {
    union { __hip_bfloat162 h2[2]; uint2 u2; } u;
    u.h2[0] = __float22bfloat162_rn(float2{wr[0].x, wr[0].y});
    u.h2[1] = __float22bfloat162_rn(float2{wr[0].z, wr[0].w});
    *(uint2*)&sB[0][sc][sq] = u.u2;
  }
  __syncthreads();

  #pragma unroll
  for (int ch = 0; ch < 12; ++ch) {
    int cur = ch & 1;
    if (ch < 11) {
      // stage next chunk into the other LDS buffer (from regs - no latency)
      union { __hip_bfloat162 h2[2]; uint2 u2; } u;
      u.h2[0] = __float22bfloat162_rn(float2{wr[ch + 1].x, wr[ch + 1].y});
      u.h2[1] = __float22bfloat162_rn(float2{wr[ch + 1].z, wr[ch + 1].w});
      *(uint2*)&sB[cur ^ 1][sc][sq] = u.u2;
      // prefetch next A fragments
      #pragma unroll
      for (int ks = 0; ks < 2; ++ks) {
        a[cur ^ 1][ks][0] = *(const short8*)(ap + (ch + 1) * 64 + ks * 32);
        a[cur ^ 1][ks][1] = *(const short8*)(ap + (ch + 1) * 64 + ks * 32 + 16 * HH);
      }
    }
    #pragma unroll
    for (int ks = 0; ks < 2; ++ks) {
      short8 b0 = *(const short8*)(&sB[cur][lr][ks * 32 + lk8]);
      short8 b1 = *(const short8*)(&sB[cur][16 + lr][ks * 32 + lk8]);
      acc[0][0] = __builtin_amdgcn_mfma_f32_16x16x32_bf16(a[cur][ks][0], b0, acc[0][0], 0, 0, 0);
      acc[0][1] = __builtin_amdgcn_mfma_f32_16x16x32_bf16(a[cur][ks][0], b1, acc[0][1], 0, 0, 0);
      acc[1][0] = __builtin_amdgcn_mfma_f32_16x16x32_bf16(a[cur][ks][1], b0, acc[1][0], 0, 0, 0);
      acc[1][1] = __builtin_amdgcn_mfma_f32_16x16x32_bf16(a[cur][ks][1], b1, acc[1][1], 0, 0, 0);
    }
    __syncthreads();
  }

  // epilogue
  int lrow = (lane >> 4) * 4;
  #pragma unroll
  for (int mi = 0; mi < 2; ++mi)
  #pragma unroll
  for (int ni = 0; ni < 2; ++ni) {
    int col  = wrow0 + ni * 16 + lr;
    int row0 = wave * 32 + mi * 16 + lrow;
    if (nb < 96) {
      float bv = b_src[col];
      #pragma unroll
      for (int r2 = 0; r2 < 4; ++r2) {
        int row = row0 + r2;
        float v = acc[mi][ni][r2] + bv;
        out[OFF_HSRC + row * 3072 + col] = v;
        Es[row * 3072 + col] = __builtin_amdgcn_exp2f(SCALEC * v);
      }
    } else if (nb < 192) {
      float bv = b_tgt[col];
      #pragma unroll
      for (int r2 = 0; r2 < 4; ++r2) {
        int row = row0 + r2;
        float v = acc[mi][ni][r2] + bv;
        out[OFF_HTGT + row * 3072 + col] = v;
        Et[row * 3072 + col] = __builtin_amdgcn_exp2f(SCALEC * v);
      }
    } else {
      float bv = dense_b[col];
      #pragma unroll
      for (int r2 = 0; r2 < 4; ++r2)
        z[(row0 + r2) * 2304 + col] = acc[mi][ni][r2] + bv;
    }
  }
}

// ---------------- pairwise relation + token-mask head ----------------
// rel[b,r,s,t] = Wsum - 2*sum_h w[h] / (1 + Es[s,h]*Et[t,h])
// 512 thr: wave g in [0,8) owns 32-h slice per chunk; lane owns 2s x 2t pairs.
#define PHC 256
__global__ __launch_bounds__(512) void pair_kernel(
    const float* __restrict__ Es, const float* __restrict__ Et,
    const float* __restrict__ w_out,
    const float* __restrict__ z, const float* __restrict__ clf_W,
    const float* __restrict__ clf_b, float* __restrict__ out)
{
  int tid = threadIdx.x;

  if (blockIdx.z == 8) {
    // token mask head
    int blk = blockIdx.y * 8 + blockIdx.x;
    int wave = tid >> 6, lane = tid & 63;
    int slot = blk * 8 + wave;
    for (int o = slot; o < 768; o += 512) {
      int b = o / 384, rem = o - b * 384;
      int t = rem >> 7, lt = rem & 127;
      const float* zr = z + (long)(b * LL + lt) * 2304 + t * HH;
      float acc = 0.f;
      for (int h = lane; h < HH; h += 64) {
        float x = zr[h];
        float th = 1.f - 2.f * __builtin_amdgcn_rcpf(1.f + __builtin_amdgcn_exp2f(SCALEC * x));
        acc = fmaf(clf_W[h], th, acc);
      }
      #pragma unroll
      for (int d = 32; d; d >>= 1) acc += __shfl_down(acc, d);
      if (lane == 0) out[OFF_MASK + o] = acc + clf_b[0];
    }
    return;
  }

  __shared__ float sA[16][PHC + 4];
  __shared__ float sB[16][PHC + 4];
  __shared__ float sRed[2048];       // [k][g][p] = k*512 + g*64 + p
  __shared__ float sWsum;

  int g = tid >> 6, lane = tid & 63;
  int sq = lane >> 3, tq = lane & 7;
  int t0 = blockIdx.x * 16, s0 = blockIdx.y * 16;
  int br = blockIdx.z, bb = br >> 2, r = br & 3;

  if (tid < 64) {
    float wsm = 0.f;
    for (int h = tid; h < HH; h += 64) wsm += w_out[h];
    #pragma unroll
    for (int d = 32; d; d >>= 1) wsm += __shfl_down(wsm, d);
    if (tid == 0) sWsum = wsm;
  }

  float a00 = 0.f, a01 = 0.f, a10 = 0.f, a11 = 0.f;

  for (int c = 0; c < HH; c += PHC) {
    // w slice for this wave+chunk -> registers (wave-uniform address)
    int offu = __builtin_amdgcn_readfirstlane(c + g * 32);
    float4 wv[8];
    #pragma unroll
    for (int q = 0; q < 8; ++q) wv[q] = *(const float4*)(w_out + offu + q * 4);

    __syncthreads();
    // stage 16 rows x 256 cols of Es and Et
    #pragma unroll
    for (int j = 0; j < 2; ++j) {
      int idx = tid * 2 + j;
      int row = idx >> 6, col4 = (idx & 63) * 4;
      *(float4*)&sA[row][col4] =
          *(const float4*)(Es + (long)(bb * LL + s0 + row) * 3072 + r * HH + c + col4);
      *(float4*)&sB[row][col4] =
          *(const float4*)(Et + (long)(bb * LL + t0 + row) * 3072 + r * HH + c + col4);
    }
    __syncthreads();

    const float* pA0 = &sA[2 * sq][g * 32];
    const float* pA1 = &sA[2 * sq + 1][g * 32];
    const float* pB0 = &sB[2 * tq][g * 32];
    const float* pB1 = &sB[2 * tq + 1][g * 32];
    #pragma unroll
    for (int hh = 0; hh < 32; hh += 4) {
      float4 e0 = *(const float4*)(pA0 + hh);
      float4 e1 = *(const float4*)(pA1 + hh);
      float4 f0 = *(const float4*)(pB0 + hh);
      float4 f1 = *(const float4*)(pB1 + hh);
      float4 vw = wv[hh >> 2];
      a00 = fmaf(vw.x, __builtin_amdgcn_rcpf(fmaf(e0.x, f0.x, 1.f)), a00);
      a01 = fmaf(vw.x, __builtin_amdgcn_rcpf(fmaf(e0.x, f1.x, 1.f)), a01);
      a10 = fmaf(vw.x, __builtin_amdgcn_rcpf(fmaf(e1.x, f0.x, 1.f)), a10);
      a11 = fmaf(vw.x, __builtin_amdgcn_rcpf(fmaf(e1.x, f1.x, 1.f)), a11);
      a00 = fmaf(vw.y, __builtin_amdgcn_rcpf(fmaf(e0.y, f0.y, 1.f)), a00);
      a01 = fmaf(vw.y, __builtin_amdgcn_rcpf(fmaf(e0.y, f1.y, 1.f)), a01);
      a10 = fmaf(vw.y, __builtin_amdgcn_rcpf(fmaf(e1.y, f0.y, 1.f)), a10);
      a11 = fmaf(vw.y, __builtin_amdgcn_rcpf(fmaf(e1.y, f1.y, 1.f)), a11);
      a00 = fmaf(vw.z, __builtin_amdgcn_rcpf(fmaf(e0.z, f0.z, 1.f)), a00);
      a01 = fmaf(vw.z, __builtin_amdgcn_rcpf(fmaf(e0.z, f1.z, 1.f)), a01);
      a10 = fmaf(vw.z, __builtin_amdgcn_rcpf(fmaf(e1.z, f0.z, 1.f)), a10);
      a11 = fmaf(vw.z, __builtin_amdgcn_rcpf(fmaf(e1.z, f1.z, 1.f)), a11);
      a00 = fmaf(vw.w, __builtin_amdgcn_rcpf(fmaf(e0.w, f0.w, 1.f)), a00);
      a01 = fmaf(vw.w, __builtin_amdgcn_rcpf(fmaf(e0.w, f1.w, 1.f)), a01);
      a10 = fmaf(vw.w, __builtin_amdgcn_rcpf(fmaf(e1.w, f0.w, 1.f)), a10);
      a11 = fmaf(vw.w, __builtin_amdgcn_rcpf(fmaf(e1.w, f1.w, 1.f)), a11);
    }
  }

  // partials: sRed[k*512 + g*64 + lane]  (stride-1 in lane -> conflict-free)
  sRed[0 * 512 + g * 64 + lane] = a00;
  sRed[1 * 512 + g * 64 + lane] = a01;
  sRed[2 * 512 + g * 64 + lane] = a10;
  sRed[3 * 512 + g * 64 + lane] = a11;
  __syncthreads();
  if (tid < 256) {
    int s = tid >> 4, t = tid & 15;
    int pp = (s >> 1) * 8 + (t >> 1);
    int sl = (s & 1) * 2 + (t & 1);
    float sum = 0.f;
    #pragma unroll
    for (int gg = 0; gg < 8; ++gg) sum += sRed[sl * 512 + gg * 64 + pp];
    out[((long)br * LL + (s0 + s)) * LL + (t0 + t)] = sWsum - 2.f * sum;
  }
}

extern "C" void kernel_launch(void* const* d_in, const int* in_sizes, int n_in,
                              void* d_out, int out_size, void* d_ws, size_t ws_size,
                              hipStream_t stream)
{
  const float* hidden  = (const float*)d_in[0];
  const float* W_src   = (const float*)d_in[1];
  const float* b_src   = (const float*)d_in[2];
  const float* W_tgt   = (const float*)d_in[3];
  const float* b_tgt   = (const float*)d_in[4];
  const float* w_out   = (const float*)d_in[5];
  const float* dense_W = (const float*)d_in[6];
  const float* dense_b = (const float*)d_in[7];
  const float* clf_W   = (const float*)d_in[8];
  const float* clf_b   = (const float*)d_in[9];
  float* out = (float*)d_out;
  char* ws = (char*)d_ws;

  unsigned short* Ab = (unsigned short*)ws;        // 256x768 bf16  [0, 384K)
  float* z  = (float*)(ws + 393216);               // 256x2304 f32  (2.36 MB)
  float* Es = (float*)(ws + 2752512);              // 256x3072 f32  (3.15 MB)
  float* Et = (float*)(ws + 5898240);              // 256x3072 f32  (3.15 MB)

  hipLaunchKernelGGL(cvta_kernel, dim3(192), dim3(256), 0, stream,
      (const float4*)hidden, (uint2*)Ab);
  hipLaunchKernelGGL(gemm_kernel, dim3(264), dim3(512), 0, stream,
      Ab, W_src, W_tgt, dense_W, b_src, b_tgt, dense_b, out, z, Es, Et);
  hipLaunchKernelGGL(pair_kernel, dim3(8, 8, 9), dim3(512), 0, stream,
      Es, Et, w_out, z, clf_W, clf_b, out + OFF_REL);
}

// Round 6
// 55.872 us; speedup vs baseline: 1.9120x; 1.0425x over previous
//
#include <hip/hip_runtime.h>
#include <hip/hip_bf16.h>

#define LL 128
#define HH 768
#define OFF_REL  0
#define OFF_MASK 131072
#define OFF_HSRC 131840
#define OFF_HTGT 918272
#define SCALEC 2.8853900817779268f   // 2*log2(e):  e^{2x} = exp2(SCALEC*x)

typedef __attribute__((ext_vector_type(8))) short short8;
typedef __attribute__((ext_vector_type(4))) float floatx4;

// ---------------- hidden fp32 -> bf16 (1.2 MB traffic) ----------------
__global__ __launch_bounds__(256) void cvta_kernel(const float4* __restrict__ hs,
                                                   uint2* __restrict__ ab)
{
  int i = blockIdx.x * 256 + threadIdx.x;   // 49152 float4s
  if (i >= 49152) return;
  float4 v = hs[i];
  union { __hip_bfloat162 h2[2]; uint2 u2; } u;
  u.h2[0] = __float22bfloat162_rn(float2{v.x, v.y});
  u.h2[1] = __float22bfloat162_rn(float2{v.z, v.w});
  ab[i] = u.u2;
}

// ---------------- GEMM: A[256x768]bf16 x W[8448x768]^T, W fp32->regs->LDS once ----------------
// grid (264, 2) x 256 thr. Block = 32 cols x 128 rows (4 waves x 32 rows).
// Whole 32x768 W panel staged bf16 in LDS; ONE barrier; free-running MFMA loop.
#define KIN 36
__global__ __launch_bounds__(256, 2) void gemm_kernel(
    const unsigned short* __restrict__ Ab,
    const float* __restrict__ Wsrc, const float* __restrict__ Wtgt,
    const float* __restrict__ Wd,
    const float* __restrict__ b_src, const float* __restrict__ b_tgt,
    const float* __restrict__ dense_b,
    float* __restrict__ out, float* __restrict__ z,
    float* __restrict__ Es, float* __restrict__ Et)
{
  __shared__ unsigned short sB[24][32][KIN];   // [ks][col][k-in-chunk], 54 KB
  int nb = blockIdx.x;
  int by = blockIdx.y;
  int tid = threadIdx.x;
  int wave = tid >> 6, lane = tid & 63;

  const float* W; int wrow0;
  if (nb < 96)       { W = Wsrc; wrow0 = nb * 32; }
  else if (nb < 192) { W = Wtgt; wrow0 = (nb - 96) * 32; }
  else               { W = Wd;   wrow0 = (nb - 192) * 32; }

  // staging role: thread -> (col, k-octet): 8 threads cover one col's 768 k's
  int sc = tid >> 3, t8 = tid & 7;
  const float* wp = W + (long)(wrow0 + sc) * HH + t8 * 4;

  // prefetch whole W panel: 24 float4 per thread, all in flight
  float4 wr[24];
  #pragma unroll
  for (int ch = 0; ch < 24; ++ch) wr[ch] = *(const float4*)(wp + ch * 32);
  #pragma unroll
  for (int ch = 0; ch < 24; ++ch) {
    union { __hip_bfloat162 h2[2]; uint2 u2; } u;
    u.h2[0] = __float22bfloat162_rn(float2{wr[ch].x, wr[ch].y});
    u.h2[1] = __float22bfloat162_rn(float2{wr[ch].z, wr[ch].w});
    *(uint2*)&sB[ch][sc][t8 * 4] = u.u2;
  }

  // MFMA fragment addressing
  int lr = lane & 15, lk8 = (lane >> 4) * 8;
  const unsigned short* ap = Ab + (by * 128 + wave * 32 + lr) * HH + lk8;

  floatx4 acc[2][2];
  #pragma unroll
  for (int mi = 0; mi < 2; ++mi)
    #pragma unroll
    for (int ni = 0; ni < 2; ++ni)
      acc[mi][ni] = (floatx4){0.f, 0.f, 0.f, 0.f};

  __syncthreads();

  #pragma unroll 4
  for (int ks = 0; ks < 24; ++ks) {
    short8 a0 = *(const short8*)(ap + ks * 32);
    short8 a1 = *(const short8*)(ap + ks * 32 + 16 * HH);
    short8 b0 = *(const short8*)(&sB[ks][lr][lk8]);
    short8 b1 = *(const short8*)(&sB[ks][16 + lr][lk8]);
    acc[0][0] = __builtin_amdgcn_mfma_f32_16x16x32_bf16(a0, b0, acc[0][0], 0, 0, 0);
    acc[0][1] = __builtin_amdgcn_mfma_f32_16x16x32_bf16(a0, b1, acc[0][1], 0, 0, 0);
    acc[1][0] = __builtin_amdgcn_mfma_f32_16x16x32_bf16(a1, b0, acc[1][0], 0, 0, 0);
    acc[1][1] = __builtin_amdgcn_mfma_f32_16x16x32_bf16(a1, b1, acc[1][1], 0, 0, 0);
  }

  // epilogue
  int lrow = (lane >> 4) * 4;
  #pragma unroll
  for (int mi = 0; mi < 2; ++mi)
  #pragma unroll
  for (int ni = 0; ni < 2; ++ni) {
    int col  = wrow0 + ni * 16 + lr;
    int row0 = by * 128 + wave * 32 + mi * 16 + lrow;
    if (nb < 96) {
      float bv = b_src[col];
      #pragma unroll
      for (int r2 = 0; r2 < 4; ++r2) {
        int row = row0 + r2;
        float v = acc[mi][ni][r2] + bv;
        out[OFF_HSRC + row * 3072 + col] = v;
        Es[row * 3072 + col] = __builtin_amdgcn_exp2f(SCALEC * v);
      }
    } else if (nb < 192) {
      float bv = b_tgt[col];
      #pragma unroll
      for (int r2 = 0; r2 < 4; ++r2) {
        int row = row0 + r2;
        float v = acc[mi][ni][r2] + bv;
        out[OFF_HTGT + row * 3072 + col] = v;
        Et[row * 3072 + col] = __builtin_amdgcn_exp2f(SCALEC * v);
      }
    } else {
      float bv = dense_b[col];
      #pragma unroll
      for (int r2 = 0; r2 < 4; ++r2)
        z[(row0 + r2) * 2304 + col] = acc[mi][ni][r2] + bv;
    }
  }
}

// ---------------- pairwise relation + token-mask head ----------------
// rel[b,r,s,t] = Wsum - 2*sum_h w[h] / (1 + Es[s,h]*Et[t,h])
// 512 thr: wave g in [0,8) owns 32-h slice per chunk; lane owns 2s x 2t pairs.
#define PHC 256
__global__ __launch_bounds__(512) void pair_kernel(
    const float* __restrict__ Es, const float* __restrict__ Et,
    const float* __restrict__ w_out,
    const float* __restrict__ z, const float* __restrict__ clf_W,
    const float* __restrict__ clf_b, float* __restrict__ out)
{
  int tid = threadIdx.x;

  if (blockIdx.z == 8) {
    // token mask head
    int blk = blockIdx.y * 8 + blockIdx.x;
    int wave = tid >> 6, lane = tid & 63;
    int slot = blk * 8 + wave;
    for (int o = slot; o < 768; o += 512) {
      int b = o / 384, rem = o - b * 384;
      int t = rem >> 7, lt = rem & 127;
      const float* zr = z + (long)(b * LL + lt) * 2304 + t * HH;
      float acc = 0.f;
      for (int h = lane; h < HH; h += 64) {
        float x = zr[h];
        float th = 1.f - 2.f * __builtin_amdgcn_rcpf(1.f + __builtin_amdgcn_exp2f(SCALEC * x));
        acc = fmaf(clf_W[h], th, acc);
      }
      #pragma unroll
      for (int d = 32; d; d >>= 1) acc += __shfl_down(acc, d);
      if (lane == 0) out[OFF_MASK + o] = acc + clf_b[0];
    }
    return;
  }

  __shared__ float sA[16][PHC + 4];
  __shared__ float sB[16][PHC + 4];
  __shared__ float sRed[2048];       // [k][g][p] = k*512 + g*64 + p
  __shared__ float sWsum;

  int g = tid >> 6, lane = tid & 63;
  int sq = lane >> 3, tq = lane & 7;
  int t0 = blockIdx.x * 16, s0 = blockIdx.y * 16;
  int br = blockIdx.z, bb = br >> 2, r = br & 3;

  if (tid < 64) {
    float wsm = 0.f;
    for (int h = tid; h < HH; h += 64) wsm += w_out[h];
    #pragma unroll
    for (int d = 32; d; d >>= 1) wsm += __shfl_down(wsm, d);
    if (tid == 0) sWsum = wsm;
  }

  float a00 = 0.f, a01 = 0.f, a10 = 0.f, a11 = 0.f;

  for (int c = 0; c < HH; c += PHC) {
    // w slice for this wave+chunk -> registers (wave-uniform address)
    int offu = __builtin_amdgcn_readfirstlane(c + g * 32);
    float4 wv[8];
    #pragma unroll
    for (int q = 0; q < 8; ++q) wv[q] = *(const float4*)(w_out + offu + q * 4);

    __syncthreads();
    // stage 16 rows x 256 cols of Es and Et
    #pragma unroll
    for (int j = 0; j < 2; ++j) {
      int idx = tid * 2 + j;
      int row = idx >> 6, col4 = (idx & 63) * 4;
      *(float4*)&sA[row][col4] =
          *(const float4*)(Es + (long)(bb * LL + s0 + row) * 3072 + r * HH + c + col4);
      *(float4*)&sB[row][col4] =
          *(const float4*)(Et + (long)(bb * LL + t0 + row) * 3072 + r * HH + c + col4);
    }
    __syncthreads();

    const float* pA0 = &sA[2 * sq][g * 32];
    const float* pA1 = &sA[2 * sq + 1][g * 32];
    const float* pB0 = &sB[2 * tq][g * 32];
    const float* pB1 = &sB[2 * tq + 1][g * 32];
    #pragma unroll
    for (int hh = 0; hh < 32; hh += 4) {
      float4 e0 = *(const float4*)(pA0 + hh);
      float4 e1 = *(const float4*)(pA1 + hh);
      float4 f0 = *(const float4*)(pB0 + hh);
      float4 f1 = *(const float4*)(pB1 + hh);
      float4 vw = wv[hh >> 2];
      a00 = fmaf(vw.x, __builtin_amdgcn_rcpf(fmaf(e0.x, f0.x, 1.f)), a00);
      a01 = fmaf(vw.x, __builtin_amdgcn_rcpf(fmaf(e0.x, f1.x, 1.f)), a01);
      a10 = fmaf(vw.x, __builtin_amdgcn_rcpf(fmaf(e1.x, f0.x, 1.f)), a10);
      a11 = fmaf(vw.x, __builtin_amdgcn_rcpf(fmaf(e1.x, f1.x, 1.f)), a11);
      a00 = fmaf(vw.y, __builtin_amdgcn_rcpf(fmaf(e0.y, f0.y, 1.f)), a00);
      a01 = fmaf(vw.y, __builtin_amdgcn_rcpf(fmaf(e0.y, f1.y, 1.f)), a01);
      a10 = fmaf(vw.y, __builtin_amdgcn_rcpf(fmaf(e1.y, f0.y, 1.f)), a10);
      a11 = fmaf(vw.y, __builtin_amdgcn_rcpf(fmaf(e1.y, f1.y, 1.f)), a11);
      a00 = fmaf(vw.z, __builtin_amdgcn_rcpf(fmaf(e0.z, f0.z, 1.f)), a00);
      a01 = fmaf(vw.z, __builtin_amdgcn_rcpf(fmaf(e0.z, f1.z, 1.f)), a01);
      a10 = fmaf(vw.z, __builtin_amdgcn_rcpf(fmaf(e1.z, f0.z, 1.f)), a10);
      a11 = fmaf(vw.z, __builtin_amdgcn_rcpf(fmaf(e1.z, f1.z, 1.f)), a11);
      a00 = fmaf(vw.w, __builtin_amdgcn_rcpf(fmaf(e0.w, f0.w, 1.f)), a00);
      a01 = fmaf(vw.w, __builtin_amdgcn_rcpf(fmaf(e0.w, f1.w, 1.f)), a01);
      a10 = fmaf(vw.w, __builtin_amdgcn_rcpf(fmaf(e1.w, f0.w, 1.f)), a10);
      a11 = fmaf(vw.w, __builtin_amdgcn_rcpf(fmaf(e1.w, f1.w, 1.f)), a11);
    }
  }

  // partials: sRed[k*512 + g*64 + lane]  (stride-1 in lane -> conflict-free)
  sRed[0 * 512 + g * 64 + lane] = a00;
  sRed[1 * 512 + g * 64 + lane] = a01;
  sRed[2 * 512 + g * 64 + lane] = a10;
  sRed[3 * 512 + g * 64 + lane] = a11;
  __syncthreads();
  if (tid < 256) {
    int s = tid >> 4, t = tid & 15;
    int pp = (s >> 1) * 8 + (t >> 1);
    int sl = (s & 1) * 2 + (t & 1);
    float sum = 0.f;
    #pragma unroll
    for (int gg = 0; gg < 8; ++gg) sum += sRed[sl * 512 + gg * 64 + pp];
    out[((long)br * LL + (s0 + s)) * LL + (t0 + t)] = sWsum - 2.f * sum;
  }
}

extern "C" void kernel_launch(void* const* d_in, const int* in_sizes, int n_in,
                              void* d_out, int out_size, void* d_ws, size_t ws_size,
                              hipStream_t stream)
{
  const float* hidden  = (const float*)d_in[0];
  const float* W_src   = (const float*)d_in[1];
  const float* b_src   = (const float*)d_in[2];
  const float* W_tgt   = (const float*)d_in[3];
  const float* b_tgt   = (const float*)d_in[4];
  const float* w_out   = (const float*)d_in[5];
  const float* dense_W = (const float*)d_in[6];
  const float* dense_b = (const float*)d_in[7];
  const float* clf_W   = (const float*)d_in[8];
  const float* clf_b   = (const float*)d_in[9];
  float* out = (float*)d_out;
  char* ws = (char*)d_ws;

  unsigned short* Ab = (unsigned short*)ws;        // 256x768 bf16  [0, 384K)
  float* z  = (float*)(ws + 393216);               // 256x2304 f32  (2.36 MB)
  float* Es = (float*)(ws + 2752512);              // 256x3072 f32  (3.15 MB)
  float* Et = (float*)(ws + 5898240);              // 256x3072 f32  (3.15 MB)

  hipLaunchKernelGGL(cvta_kernel, dim3(192), dim3(256), 0, stream,
      (const float4*)hidden, (uint2*)Ab);
  hipLaunchKernelGGL(gemm_kernel, dim3(264, 2), dim3(256), 0, stream,
      Ab, W_src, W_tgt, dense_W, b_src, b_tgt, dense_b, out, z, Es, Et);
  hipLaunchKernelGGL(pair_kernel, dim3(8, 8, 9), dim3(512), 0, stream,
      Es, Et, w_out, z, clf_W, clf_b, out + OFF_REL);
}